// Round 1
// baseline (134.632 us; speedup 1.0000x reference)
//
#include <hip/hip_runtime.h>
#include <stdint.h>

// Problem constants: S=512, B=64, H=8, K=12, P=9, L=137, T=4096, THRESH=4

__global__ __launch_bounds__(256) void softram_parity_kernel(
    const int* __restrict__ tokens,   // (S=512, B=64) int32 in {0,1}
    const int* __restrict__ conn,     // (H=8, B=64, K=12) int32 in [0,137)
    const float* __restrict__ ram,    // (H=8, B=64, T=4096) float in {0.0,1.0}
    uint32_t* __restrict__ wsp)       // packed parity bits: [hb][chunk][2] u32
{
    __shared__ uint32_t table[128];              // 4096-bit RAM table for this (h,b)
    __shared__ unsigned long long tokrow[512];   // token row bitmasks
    __shared__ unsigned short AqL[512], AkL[512], ArL[512];

    const int tid  = threadIdx.x;
    const int lane = tid & 63;
    const int w    = tid >> 6;        // wave id 0..3
    const int hb   = blockIdx.x;      // h*64 + b

    // ---- Phase 1a: pack ram[h][b][0..4095] into 128 u32 words via ballot ----
    const float* ramp = ram + (size_t)hb * 4096;
    #pragma unroll
    for (int c = 0; c < 16; ++c) {
        float v = ramp[c * 256 + tid];
        unsigned long long m = __ballot(v > 0.5f);
        if (lane == 0) {
            table[c * 8 + w * 2]     = (uint32_t)m;
            table[c * 8 + w * 2 + 1] = (uint32_t)(m >> 32);
        }
    }

    // ---- Phase 1b: pack token rows into u64 bitmasks (coalesced loads) ----
    #pragma unroll 4
    for (int c = 0; c < 128; ++c) {
        int v = tokens[c * 256 + tid];           // s = c*4 + w, bit = lane
        unsigned long long m = __ballot(v != 0);
        if (lane == 0) tokrow[c * 4 + w] = m;
    }
    __syncthreads();

    // ---- Phase 2: per-position partial addresses Aq/Ak/Ar ----
    const int* cp = conn + hb * 12;              // uniform -> scalar loads
    int ck[12];
    #pragma unroll
    for (int k = 0; k < 12; ++k) ck[k] = cp[k];

    for (int s = tid; s < 512; s += 256) {
        unsigned long long row = tokrow[s];
        int aq = 0, ak = 0, ar = 0;
        #pragma unroll
        for (int k = 0; k < 12; ++k) {
            int c = ck[k];                       // wave-uniform -> scalar branches
            if (c < 64)       aq |= (int)((row >> c) & 1ull) << k;
            else if (c < 128) ak |= (int)((row >> (c - 64)) & 1ull) << k;
            else              ar |= ((s >> (c - 128)) & 1) << k;
        }
        AqL[s] = (unsigned short)aq;
        AkL[s] = (unsigned short)ak;
        ArL[s] = (unsigned short)ar;
    }
    __syncthreads();

    // ---- Phase 3: parity rows. Wave w does chunks {w, 7-w}: 576 steps each ----
    for (int cc = 0; cc < 2; ++cc) {
        const int c = cc ? (7 - w) : w;          // row chunk: rows [64c, 64c+64)
        const int i = c * 64 + lane;
        const int aq = (int)AqL[i];
        uint32_t acc = 0;

        // full sub-blocks: j in [0, 64c), all lanes active (j <= 64c-1 < i_min? no:
        // i >= 64c > j always here)
        for (int j0 = 0; j0 < c * 64; j0 += 64) {
            int akv = (int)AkL[j0 + lane];
            #pragma unroll
            for (int jj = 0; jj < 64; ++jj) {
                int sak = __builtin_amdgcn_readlane(akv, jj);   // wave-uniform Ak[j]
                int d = i - j0 - jj;                            // >= 1 here
                int addr = aq + sak + (int)ArL[d];
                acc ^= table[addr >> 5] >> (addr & 31);         // parity in bit 0
            }
        }
        // tail sub-block: j in [64c, 64c+64), active iff jj <= lane
        {
            int akv = (int)AkL[c * 64 + lane];
            #pragma unroll
            for (int jj = 0; jj < 64; ++jj) {
                int sak = __builtin_amdgcn_readlane(akv, jj);
                int d = lane - jj;
                int dm = d < 0 ? 0 : d;
                int addr = aq + sak + (int)ArL[dm];
                uint32_t bit = table[addr >> 5] >> (addr & 31);
                acc ^= (d >= 0) ? bit : 0u;
            }
        }
        acc &= 1u;
        unsigned long long m = __ballot(acc != 0);   // bit lane = parity(row 64c+lane)
        if (lane == 0) {
            wsp[(hb * 8 + c) * 2]     = (uint32_t)m;
            wsp[(hb * 8 + c) * 2 + 1] = (uint32_t)(m >> 32);
        }
    }
}

__global__ __launch_bounds__(256) void softram_vote_kernel(
    const uint32_t* __restrict__ wsp, float* __restrict__ out)
{
    int t = blockIdx.x * 256 + threadIdx.x;      // t = i*64 + b, 32768 total
    int b = t & 63;
    int i = t >> 6;
    int sum = 0;
    #pragma unroll
    for (int h = 0; h < 8; ++h) {
        int hb = h * 64 + b;
        uint32_t wv = wsp[(hb * 8 + (i >> 6)) * 2 + ((i >> 5) & 1)];
        sum += (wv >> (i & 31)) & 1u;
    }
    out[t] = (sum > 4) ? 1.0f : 0.0f;            // THRESH = H/2 = 4
}

extern "C" void kernel_launch(void* const* d_in, const int* in_sizes, int n_in,
                              void* d_out, int out_size, void* d_ws, size_t ws_size,
                              hipStream_t stream) {
    const int*   tokens = (const int*)d_in[0];   // (512, 64)
    const int*   conn   = (const int*)d_in[1];   // (8, 64, 12)
    const float* ram    = (const float*)d_in[2]; // (8, 64, 4096)
    float*       out    = (float*)d_out;         // (512, 64)
    uint32_t*    wsp    = (uint32_t*)d_ws;       // 8192 u32 = 32 KB parity bits

    softram_parity_kernel<<<512, 256, 0, stream>>>(tokens, conn, ram, wsp);
    softram_vote_kernel<<<128, 256, 0, stream>>>(wsp, out);
}

// Round 2
// 104.376 us; speedup vs baseline: 1.2899x; 1.2899x over previous
//
#include <hip/hip_runtime.h>
#include <stdint.h>

// S=512, B=64, H=8, K=12, P=9, L=137, T=4096, THRESH=4
// Workspace layout (u32 units):
//   [0, 65536)       packed ram tables: 128 u32 per hb (hb-major)   = 256 KB
//   [65536, 66560)   packed token rows: 512 u64                     = 4 KB
//   [66560, 74752)   parity bits: [hb][chunk(8)][2] u32             = 32 KB
#define WS_TABLE  0
#define WS_TOKROW 65536
#define WS_PAR    66560

// ---- Kernel 0: pack ram bits and token rows once into workspace ----
__global__ __launch_bounds__(256) void softram_pack_kernel(
    const int* __restrict__ tokens,   // (512, 64)
    const float* __restrict__ ram,    // (8, 64, 4096) values in {0,1}
    uint32_t* __restrict__ ws)
{
    const int tid = threadIdx.x, lane = tid & 63, w = tid >> 6;
    if (blockIdx.x < 512) {
        const int hb = blockIdx.x;
        const float* ramp = ram + (size_t)hb * 4096;
        uint32_t* tp = ws + WS_TABLE + hb * 128;
        #pragma unroll
        for (int c = 0; c < 16; ++c) {
            float v = ramp[c * 256 + tid];
            unsigned long long m = __ballot(v > 0.5f);
            if (lane == 0) {
                tp[c * 8 + w * 2]     = (uint32_t)m;
                tp[c * 8 + w * 2 + 1] = (uint32_t)(m >> 32);
            }
        }
    } else {
        const int r = blockIdx.x - 512;          // 0..7, 16 row-groups each
        unsigned long long* tokp = (unsigned long long*)(ws + WS_TOKROW);
        for (int c = r * 16; c < r * 16 + 16; ++c) {
            int v = tokens[c * 256 + tid];       // s = c*4 + w, bit = lane (=b)
            unsigned long long m = __ballot(v != 0);
            if (lane == 0) tokp[c * 4 + w] = m;
        }
    }
}

// ---- Kernel 1: parity. 4 blocks per hb; block q owns chunks {q, 7-q};
//      each chunk is split across 2 waves by interleaved j-sub-blocks. ----
__global__ __launch_bounds__(256) void softram_parity_kernel(
    const int* __restrict__ conn,     // (8, 64, 12)
    uint32_t* __restrict__ ws)
{
    __shared__ uint32_t table[128];
    __shared__ unsigned long long tokrow[512];
    __shared__ unsigned short AqL[512], AkL[512], ArL[512];
    __shared__ unsigned long long parbuf[4];

    const int tid  = threadIdx.x;
    const int lane = tid & 63;
    const int w    = tid >> 6;
    const int hb   = blockIdx.x >> 2;
    const int q    = blockIdx.x & 3;

    // stage packed table + token rows from workspace
    if (tid < 128) table[tid] = ws[WS_TABLE + hb * 128 + tid];
    {
        const unsigned long long* tokp = (const unsigned long long*)(ws + WS_TOKROW);
        tokrow[tid]       = tokp[tid];
        tokrow[tid + 256] = tokp[tid + 256];
    }
    __syncthreads();

    // per-position partial addresses (bits of addr are disjoint across q/k/r)
    const int* cp = conn + hb * 12;
    int ck[12];
    #pragma unroll
    for (int k = 0; k < 12; ++k) ck[k] = cp[k];
    #pragma unroll
    for (int rep = 0; rep < 2; ++rep) {
        int s = tid + rep * 256;
        unsigned long long row = tokrow[s];
        int aq = 0, ak = 0, ar = 0;
        #pragma unroll
        for (int k = 0; k < 12; ++k) {
            int c = ck[k];                        // wave-uniform -> scalar branch
            if (c < 64)       aq |= (int)((row >> c) & 1ull) << k;
            else if (c < 128) ak |= (int)((row >> (c - 64)) & 1ull) << k;
            else              ar |= ((s >> (c - 128)) & 1) << k;
        }
        AqL[s] = (unsigned short)aq;
        AkL[s] = (unsigned short)ak;
        ArL[s] = (unsigned short)ar;
    }
    __syncthreads();

    // waves 0,1 -> chunk q (halves 0,1); waves 2,3 -> chunk 7-q (halves 0,1)
    const int c  = (w < 2) ? q : (7 - q);
    const int hh = w & 1;
    const int i  = c * 64 + lane;                // this lane's output row
    const int aq = (int)AqL[i];
    uint32_t acc = 0;

    // full sub-blocks sb in [0, c), this wave takes sb ≡ hh (mod 2)
    for (int sb = hh; sb < c; sb += 2) {
        int akv = (int)AkL[sb * 64 + lane];
        #pragma unroll
        for (int jj = 0; jj < 64; ++jj) {
            int sak = __builtin_amdgcn_readlane(akv, jj);   // wave-uniform Ak[j]
            int d = i - sb * 64 - jj;                       // >= 1 here
            int addr = aq + sak + (int)ArL[d];
            acc ^= table[addr >> 5] >> (addr & 31);         // parity in bit 0
        }
    }
    // tail sub-block sb == c (j <= i masking), owned by the matching-parity wave
    if (hh == (c & 1)) {
        int akv = (int)AkL[c * 64 + lane];
        #pragma unroll
        for (int jj = 0; jj < 64; ++jj) {
            int sak = __builtin_amdgcn_readlane(akv, jj);
            int d = lane - jj;
            int dm = d < 0 ? 0 : d;
            int addr = aq + sak + (int)ArL[dm];
            uint32_t bit = table[addr >> 5] >> (addr & 31);
            acc ^= (d >= 0) ? bit : 0u;
        }
    }
    acc &= 1u;
    unsigned long long m = __ballot(acc != 0);
    if (lane == 0) parbuf[w] = m;
    __syncthreads();

    if (tid == 0) {
        unsigned long long m0 = parbuf[0] ^ parbuf[1];      // chunk q
        unsigned long long m1 = parbuf[2] ^ parbuf[3];      // chunk 7-q
        uint32_t* wp = ws + WS_PAR;
        wp[(hb * 8 + q) * 2]           = (uint32_t)m0;
        wp[(hb * 8 + q) * 2 + 1]       = (uint32_t)(m0 >> 32);
        wp[(hb * 8 + (7 - q)) * 2]     = (uint32_t)m1;
        wp[(hb * 8 + (7 - q)) * 2 + 1] = (uint32_t)(m1 >> 32);
    }
}

// ---- Kernel 2: majority vote over heads ----
__global__ __launch_bounds__(256) void softram_vote_kernel(
    const uint32_t* __restrict__ ws, float* __restrict__ out)
{
    int t = blockIdx.x * 256 + threadIdx.x;      // t = i*64 + b, 32768 total
    int b = t & 63;
    int i = t >> 6;
    const uint32_t* wp = ws + WS_PAR;
    int sum = 0;
    #pragma unroll
    for (int h = 0; h < 8; ++h) {
        int hb = h * 64 + b;
        uint32_t wv = wp[(hb * 8 + (i >> 6)) * 2 + ((i >> 5) & 1)];
        sum += (wv >> (i & 31)) & 1u;
    }
    out[t] = (sum > 4) ? 1.0f : 0.0f;            // THRESH = H/2 = 4
}

extern "C" void kernel_launch(void* const* d_in, const int* in_sizes, int n_in,
                              void* d_out, int out_size, void* d_ws, size_t ws_size,
                              hipStream_t stream) {
    const int*   tokens = (const int*)d_in[0];   // (512, 64)
    const int*   conn   = (const int*)d_in[1];   // (8, 64, 12)
    const float* ram    = (const float*)d_in[2]; // (8, 64, 4096)
    float*       out    = (float*)d_out;         // (512, 64)
    uint32_t*    ws     = (uint32_t*)d_ws;       // needs ~300 KB

    softram_pack_kernel<<<520, 256, 0, stream>>>(tokens, ram, ws);
    softram_parity_kernel<<<2048, 256, 0, stream>>>(conn, ws);
    softram_vote_kernel<<<128, 256, 0, stream>>>(ws, out);
}